// Round 10
// baseline (602.337 us; speedup 1.0000x reference)
//
#include <hip/hip_runtime.h>
#include <cstdint>
#include <cstddef>

typedef unsigned short u16;
typedef __attribute__((ext_vector_type(8))) short bf16x8;   // 8 bf16 = 4 VGPRs
typedef __attribute__((ext_vector_type(4))) float f32x4;    // MFMA accumulator

#define DEVFN static __device__ __forceinline__

DEVFN u16 f2bf(float f) {
  unsigned u = __float_as_uint(f);
  unsigned r = (u + 0x7FFFu + ((u >> 16) & 1u)) >> 16;   // RTN-even
  return (u16)r;
}

// async global->LDS, 16B/lane. LDS dest = wave-uniform base + lane*16 (m104/m108).
DEVFN void gload16(const void* g, void* l) {
  __builtin_amdgcn_global_load_lds(
      (const __attribute__((address_space(1))) void*)g,
      (__attribute__((address_space(3))) void*)l, 16, 0, 0);
}

// counted waits + raw barrier (compiler memory fences keep LDS ops ordered)
#define WAITVM(n) asm volatile("s_waitcnt vmcnt(" #n ")" ::: "memory")
#define BARRIER() do { asm volatile("" ::: "memory"); \
                       __builtin_amdgcn_s_barrier();   \
                       asm volatile("" ::: "memory"); } while (0)
// Wave-internal LDS write->read fence (R9, rule #18): cross-lane P round-trip is
// invisible to LLVM's per-lane alias analysis.
#define FENCE_LDS() do { asm volatile("s_waitcnt lgkmcnt(0)" ::: "memory"); \
                         __builtin_amdgcn_sched_barrier(0); } while (0)

// ---------------- merged prep: converts + wqkv row-permute + cos/sin table ----------------
// wqkv q/k rows interleaved per head: d<64 -> 2d, d>=64 -> 2(d-64)+1  (QK^T invariant).
// cs[l*64+m] = (cos(l,m), sin(l,m))
__global__ void prep(const float* __restrict__ x, const float* __restrict__ wqkv,
                     const float* __restrict__ wout, const float* __restrict__ cosp,
                     const float* __restrict__ sinp, u16* __restrict__ xb,
                     u16* __restrict__ wqkvb, u16* __restrict__ woutb,
                     float2* __restrict__ cs) {
  constexpr int X4 = 4194304;      // x elems/4
  constexpr int W4 = 3145728;      // wqkv elems/4
  constexpr int O4 = 1048576;      // wout elems/4
  int i = blockIdx.x * blockDim.x + threadIdx.x;
  if (i < X4) {
    float4 v = ((const float4*)x)[i];
    unsigned long long w = (unsigned long long)f2bf(v.x)
        | ((unsigned long long)f2bf(v.y) << 16)
        | ((unsigned long long)f2bf(v.z) << 32)
        | ((unsigned long long)f2bf(v.w) << 48);
    *(unsigned long long*)(xb + (size_t)i * 4) = w;
  } else if (i < X4 + W4) {
    int j = i - X4;
    int base = j * 4;
    int e = base >> 11, col = base & 2047;
    int e2;
    if (e < 4096) {
      int part = e >> 11, loc = e & 2047;
      int h = loc >> 7, d = loc & 127;
      int d2 = (d < 64) ? 2 * d : 2 * (d - 64) + 1;
      e2 = part * 2048 + h * 128 + d2;
    } else {
      e2 = e;                      // v rows unpermuted
    }
    float4 v = *(const float4*)&wqkv[(size_t)base];
    unsigned long long w = (unsigned long long)f2bf(v.x)
        | ((unsigned long long)f2bf(v.y) << 16)
        | ((unsigned long long)f2bf(v.z) << 32)
        | ((unsigned long long)f2bf(v.w) << 48);
    *(unsigned long long*)(wqkvb + (size_t)e2 * 2048 + col) = w;
  } else if (i < X4 + W4 + O4) {
    int j = i - X4 - W4;
    float4 v = ((const float4*)wout)[j];
    unsigned long long w = (unsigned long long)f2bf(v.x)
        | ((unsigned long long)f2bf(v.y) << 16)
        | ((unsigned long long)f2bf(v.z) << 32)
        | ((unsigned long long)f2bf(v.w) << 48);
    *(unsigned long long*)(woutb + (size_t)j * 4) = w;
  } else {
    int k = i - X4 - W4 - O4;      // < 32768
    int ld4 = k * 4;
#pragma unroll
    for (int u = 0; u < 4; u++) {
      int ld = ld4 + u;
      int l = ld >> 6, d = ld & 63;
      cs[ld] = make_float2(cosp[(size_t)l * 128 + d], sinp[(size_t)l * 128 + d]);
    }
  }
}

// ========== 256x256 GEMM core, R12: m201-style 4-phase schedule on the R11 layout ==========
// BM=BN=256, BK=64, 512 thr = 8 waves (2M x 4N), wave output 128x64 = acc[8][4].
// LDS: A[2][256*64] + B[2][256*64] bf16 = 128 KB, dbuf by K-tile parity (R4/R11 verified).
// R10/R11 lesson: barrier count isn't the poison (m201 runs 8 bars/K-tile at 62% MfmaUtil);
// reads-AFTER-barrier is (serializes 12-16 ds_read + lgkm in front of each MFMA cluster).
// m201 phase shape: {ds_read this phase's frags || stage issue -> [wait] -> BAR ->
// setprio 16 MFMA setprio -> BAR} — reads overlap the barrier wait.
// Phase p reads A-quad p (+ all B frags at p=0, held in regs); staging of tile t+1 spread
// B0|B1|A01|A23 across phases. Ledger (entering tile: 3 outstanding = A123(t)):
//   ph1: issue B0(t+1)[2] -> 5;  WAITVM(4) drains A1(t)
//   ph2: issue B1(t+1)[2] -> 6;  WAITVM(5) drains A2(t)
//   ph3: issue A0,A1(t+1)[2]->7; WAITVM(6) drains A3(t)
//   ph4: issue A2,A3(t+1)[2]->8; WAITVM(3) drains B(t+1)+A0(t+1) for next ph1's reads
// Never 0 in main loop (peeled last tile 2/1/0/0); min staging lead 2-3 phases.
// WAR: every staged region's opposite-parity reads retired >=6 barriers earlier.
enum { M_F32OUT = 0, M_ROPE = 1, M_VT = 2 };

DEVFN bf16x8 rdfrag(const u16* buf, int row, int chunk) {
  return *(const bf16x8*)&buf[row * 64 + (((chunk ^ (row & 7)) & 7) << 3)];
}

template <int Q>
DEVFN void read_frags(const u16* Ac, const u16* Bc, int wm, int wn, int quad, int l16,
                      bf16x8 (&bfr)[4][2], bf16x8 (&af)[2][2]) {
  if (Q == 0) {
#pragma unroll
    for (int j = 0; j < 4; j++)
#pragma unroll
      for (int kk = 0; kk < 2; kk++)
        bfr[j][kk] = rdfrag(Bc, wn * 64 + j * 16 + l16, kk * 4 + quad);
  }
#pragma unroll
  for (int i2 = 0; i2 < 2; i2++)
#pragma unroll
    for (int kk = 0; kk < 2; kk++)
      af[i2][kk] = rdfrag(Ac, wm * 128 + (Q * 2 + i2) * 16 + l16, kk * 4 + quad);
}

template <int MODE, int Q>
DEVFN void mfma_only(bf16x8 (&bfr)[4][2], bf16x8 (&af)[2][2], f32x4 (&acc)[8][4]) {
  __builtin_amdgcn_s_setprio(1);
#pragma unroll
  for (int kk = 0; kk < 2; kk++)
#pragma unroll
    for (int i2 = 0; i2 < 2; i2++)
#pragma unroll
      for (int j = 0; j < 4; j++) {
        if (MODE == M_VT)
          acc[Q * 2 + i2][j] = __builtin_amdgcn_mfma_f32_16x16x32_bf16(
              bfr[j][kk], af[i2][kk], acc[Q * 2 + i2][j], 0, 0, 0);
        else
          acc[Q * 2 + i2][j] = __builtin_amdgcn_mfma_f32_16x16x32_bf16(
              af[i2][kk], bfr[j][kk], acc[Q * 2 + i2][j], 0, 0, 0);
      }
  __builtin_amdgcn_s_setprio(0);
}

template <int MODE>
DEVFN void gemm256_core(const u16* __restrict__ A, const u16* __restrict__ Bt,
                        void* __restrict__ Cv, const float2* __restrict__ cs,
                        int N, int m0, int n0, u16* As, u16* Bs) {
  int tid = threadIdx.x;
  int wv = tid >> 6, lane = tid & 63, quad = lane >> 4, l16 = lane & 15;
  int wm = wv >> 2, wn = wv & 3;

  // per-thread pre-swizzled global source pointers (advance by k elems per tile)
  const u16* pB[2][2];
  const u16* pA[4];
#pragma unroll
  for (int h = 0; h < 2; h++)
#pragma unroll
    for (int o = 0; o < 2; o++) {
      int r = h * 128 + o * 64 + wv * 8 + (lane >> 3);
      int ck = (lane & 7) ^ (r & 7);
      pB[h][o] = Bt + (size_t)(n0 + r) * 2048 + ck * 8;
    }
#pragma unroll
  for (int q = 0; q < 4; q++) {
    int rb = (wv < 4) ? (q * 32 + wv * 8) : (128 + q * 32 + (wv - 4) * 8);
    int r = rb + (lane >> 3);
    int ck = (lane & 7) ^ (r & 7);
    pA[q] = A + (size_t)(m0 + r) * 2048 + ck * 8;
  }

#define STAGE_B(h, buf, kk) do {                                    \
    int rb0_ = (h) * 128 + wv * 8;                                  \
    gload16(pB[h][0] + (kk), &(buf)[rb0_ * 64]);                    \
    gload16(pB[h][1] + (kk), &(buf)[(rb0_ + 64) * 64]); } while (0)
#define STAGE_A(q, buf, kk) do {                                    \
    int rb_ = ((wv < 4) ? ((q) * 32 + wv * 8)                       \
                        : (128 + (q) * 32 + (wv - 4) * 8));         \
    gload16(pA[q] + (kk), &(buf)[rb_ * 64]); } while (0)

  f32x4 acc[8][4] = {};
  bf16x8 bfr[4][2];
  bf16x8 af[2][2];

  // prologue: stage tile 0 into buffer 0 (issue order = ledger order), land B+A0
  STAGE_B(0, Bs, 0);
  STAGE_B(1, Bs, 0);
  STAGE_A(0, As, 0);
  STAGE_A(1, As, 0);
  STAGE_A(2, As, 0);
  STAGE_A(3, As, 0);
  WAITVM(3); BARRIER();                        // B(0)+A0(0) landed; 3 outstanding

  for (int t = 0; t < 31; t++) {
    const u16* Ac = As + (t & 1) * 16384;
    const u16* Bc = Bs + (t & 1) * 16384;
    u16* An = As + ((t + 1) & 1) * 16384;
    u16* Bn = Bs + ((t + 1) & 1) * 16384;
    int kn = (t + 1) * 64;
    // ph1
    read_frags<0>(Ac, Bc, wm, wn, quad, l16, bfr, af);
    STAGE_B(0, Bn, kn);
    WAITVM(4); BARRIER();
    mfma_only<MODE, 0>(bfr, af, acc);
    BARRIER();
    // ph2
    read_frags<1>(Ac, Bc, wm, wn, quad, l16, bfr, af);
    STAGE_B(1, Bn, kn);
    WAITVM(5); BARRIER();
    mfma_only<MODE, 1>(bfr, af, acc);
    BARRIER();
    // ph3
    read_frags<2>(Ac, Bc, wm, wn, quad, l16, bfr, af);
    STAGE_A(0, An, kn);
    STAGE_A(1, An, kn);
    WAITVM(6); BARRIER();
    mfma_only<MODE, 2>(bfr, af, acc);
    BARRIER();
    // ph4
    read_frags<3>(Ac, Bc, wm, wn, quad, l16, bfr, af);
    STAGE_A(2, An, kn);
    STAGE_A(3, An, kn);
    WAITVM(3); BARRIER();                      // next ph1's B+A0 landed
    mfma_only<MODE, 3>(bfr, af, acc);
    BARRIER();
  }
  {  // peeled last tile (parity 1), no staging: waits 2/1/0/0
    const u16* Ac = As + 16384;
    const u16* Bc = Bs + 16384;
    read_frags<0>(Ac, Bc, wm, wn, quad, l16, bfr, af);
    WAITVM(2); BARRIER();
    mfma_only<MODE, 0>(bfr, af, acc);
    BARRIER();
    read_frags<1>(Ac, Bc, wm, wn, quad, l16, bfr, af);
    WAITVM(1); BARRIER();
    mfma_only<MODE, 1>(bfr, af, acc);
    BARRIER();
    read_frags<2>(Ac, Bc, wm, wn, quad, l16, bfr, af);
    WAITVM(0); BARRIER();
    mfma_only<MODE, 2>(bfr, af, acc);
    BARRIER();
    read_frags<3>(Ac, Bc, wm, wn, quad, l16, bfr, af);
    BARRIER();
    mfma_only<MODE, 3>(bfr, af, acc);
  }
#undef STAGE_B
#undef STAGE_A

  // ---- epilogue: C/D layout col = lane&15, row = quad*4 + reg (m89/m91 verified) ----
  if (MODE == M_F32OUT) {
    float* C = (float*)Cv;
#pragma unroll
    for (int i = 0; i < 8; i++)
#pragma unroll
      for (int r = 0; r < 4; r++) {
        size_t row = (size_t)(m0 + wm * 128 + i * 16 + quad * 4 + r);
#pragma unroll
        for (int j = 0; j < 4; j++)
          C[row * N + (n0 + wn * 64 + j * 16 + l16)] = acc[i][j][r];
      }
  } else if (MODE == M_ROPE) {
    constexpr float QSCALE = 1.4426950408889634f * 0.08838834764831845f;
    const float scale = (n0 >> 11) ? 1.0f : QSCALE;   // q gets log2e/sqrt(128)
    u16* C = (u16*)Cv;
#pragma unroll
    for (int i = 0; i < 8; i++)
#pragma unroll
      for (int r = 0; r < 4; r++) {
        int row = m0 + wm * 128 + i * 16 + quad * 4 + r;
        int l = row & 2047;
#pragma unroll
        for (int j = 0; j < 4; j++) {
          int col = n0 + wn * 64 + j * 16 + l16;
          int dm = (col & 127) >> 1;
          float2 csv = cs[l * 64 + dm];
          float v = acc[i][j][r];
          float pv = __shfl_xor(v, 1);                 // partner lane (col^1)
          float sg = (l16 & 1) ? csv.y : -csv.y;       // even: -sin, odd: +sin
          C[(size_t)row * 4096 + col] = f2bf((v * csv.x + pv * sg) * scale);
        }
      }
  } else {
    // VT: swapped operands -> acc holds C^T; row = v-channel, col = token. vt[bh][d][l].
    u16* vt = (u16*)Cv;
#pragma unroll
    for (int j = 0; j < 4; j++)
#pragma unroll
      for (int r = 0; r < 4; r++) {
        int vch = n0 + wn * 64 + j * 16 + quad * 4 + r;   // 0..2047
        int h = vch >> 7, d = vch & 127;
#pragma unroll
        for (int i = 0; i < 8; i++) {
          int token = m0 + wm * 128 + i * 16 + l16;
          int b = token >> 11, lloc = token & 2047;
          vt[((size_t)(b * 16 + h)) * 262144 + (size_t)d * 2048 + lloc] =
              f2bf(acc[i][j][r]);
        }
      }
  }
}

// Merged QKV GEMM: bx<16 -> RoPE epilogue into qkv (stride 4096); bx>=16 -> V^T.
// XCD y-striping: each XCD owns a 4-row stripe of M-tiles (A rows L2-resident).
__global__ __launch_bounds__(512, 2) void gemm_qkv(const u16* __restrict__ xb,
                                                   const u16* __restrict__ wqkvb,
                                                   u16* __restrict__ qkvo,
                                                   u16* __restrict__ vto,
                                                   const float2* __restrict__ cs) {
  __shared__ u16 As[32768];
  __shared__ u16 Bs[32768];
  int id = blockIdx.x;
  int xcd = id & 7, sub = id >> 3;      // sub 0..95
  int bx = sub % 24, by = xcd * 4 + sub / 24;
  if (bx < 16)
    gemm256_core<M_ROPE>(xb, wqkvb, qkvo, cs, 0, by * 256, bx * 256, As, Bs);
  else
    gemm256_core<M_VT>(xb, wqkvb + (size_t)4096 * 2048, vto, nullptr, 0,
                       by * 256, (bx - 16) * 256, As, Bs);
}

__global__ __launch_bounds__(512, 2) void gemm_out_k(const u16* __restrict__ A,
                                                     const u16* __restrict__ Bt,
                                                     float* __restrict__ C) {
  __shared__ u16 As[32768];
  __shared__ u16 Bs[32768];
  int id = blockIdx.x;
  int xcd = id & 7, sub = id >> 3;      // sub 0..31
  int bx = sub % 8, by = xcd * 4 + sub / 8;
  gemm256_core<M_F32OUT>(A, Bt, C, nullptr, 2048, by * 256, bx * 256, As, Bs);
}

// ---------------- fused flash attention (fixed-base softmax, no online max) ----------------
// R9 (verified): 256 thr / 4 waves / 32 q-rows per wave (each K/V fragment read feeds
// TWO row-tiles), KVBLK=32, double-buffered K (2x8KB) + V (2x8KB) + padded P
// (128 x 40 = 10KB) = 43KB LDS -> 3 blocks/CU, 12 waves/CU. FENCE_LDS between the
// P-write loop and pf reads (R8 failure: compiler hoisted the cross-lane ds_read).
DEVFN int swz(int row, int chunk)   { return row * 128 + ((chunk ^ (row & 15)) << 3); } // 256B rows
DEVFN int swz32(int row, int chunk) { return row * 32  + (((chunk ^ (row & 3)) & 3) << 3); } // 64B rows

__global__ __launch_bounds__(256, 3) void attn_fused(const u16* __restrict__ qkv,
                                                     const u16* __restrict__ vt,
                                                     u16* __restrict__ out) {
  // S layout (u16 units): [0,4096)=Kb0 [4096,8192)=Kb1
  //                       [8192,12288)=Vb0 [12288,16384)=Vb1
  //                       [16384,21504)=P (128 rows x 40 elems, 80B stride: bank-spread)
  __shared__ u16 S[21504];                     // 43008 B
  u16* const Pb = S + 16384;
  int tid = threadIdx.x;
  int wv = tid >> 6, lane = tid & 63, quad = lane >> 4, l16 = lane & 15;
  int id = blockIdx.x;
  int xcd = id & 7, sub = id >> 3;             // sub 0..127
  int bh = ((sub >> 4) << 3) | xcd;            // 8 bh per XCD, all 16 qtiles local
  int qt = sub & 15;
  int b = bh >> 4, hh = bh & 15;
  const u16* qptr = qkv + (size_t)b * 2048 * 4096 + hh * 128;
  const u16* kptr = qptr + 2048;
  const u16* vptr = vt + (size_t)bh * 262144;
  int q0 = qt * 128;

  // ---- Q staging: 128 rows x 256B through S[0..16384), then pull to regs ----
#pragma unroll
  for (int j = 0; j < 8; j++) {
    int rb = wv * 4 + j * 16;
    int r = rb + (lane >> 4);
    int ck = (lane & 15) ^ (r & 15);
    gload16(&qptr[(size_t)(q0 + r) * 4096 + ck * 8], &S[rb * 128]);
  }
  __syncthreads();
  bf16x8 qf[2][4];
#pragma unroll
  for (int hf = 0; hf < 2; hf++)
#pragma unroll
    for (int ks = 0; ks < 4; ks++)
      qf[hf][ks] = *(const bf16x8*)&S[swz(wv * 32 + hf * 16 + l16, ks * 4 + quad)];
  __syncthreads();                             // qf reads done before kt=0 staging

  f32x4 o[2][8] = {};
  float l[2][4] = {{0.f, 0.f, 0.f, 0.f}, {0.f, 0.f, 0.f, 0.f}};

  // prologue: stage kt=0 into Kb0/Vb0 (K: 32 rows x 256B; V^T: 128 rows x 64B)
#pragma unroll
  for (int j = 0; j < 2; j++) {
    int rbk = wv * 4 + j * 16;
    int rk = rbk + (lane >> 4);
    int ckk = (lane & 15) ^ (rk & 15);
    gload16(&kptr[(size_t)rk * 4096 + ckk * 8], &S[rbk * 128]);
    int rbv = wv * 16 + j * 64;
    int rv = rbv + (lane >> 2);
    int ckv = (lane & 3) ^ (rv & 3);
    gload16(&vptr[(size_t)rv * 2048 + ckv * 8], &S[8192 + rbv * 32]);
  }

  for (int kt = 0; kt < 64; kt++) {
    int cur = kt & 1;
    const u16* Kc = S + cur * 4096;
    const u16* Vc = S + 8192 + cur * 4096;
    __syncthreads();   // auto vmcnt(0): drains cur-tile loads (1 iter old) + prior reads
    if (kt < 63) {     // prefetch kt+1 into the other buffer set
      int kk0 = (kt + 1) * 32;
      u16* kb = S + (cur ^ 1) * 4096;
      u16* vb = S + 8192 + (cur ^ 1) * 4096;
#pragma unroll
      for (int j = 0; j < 2; j++) {
        int rbk = wv * 4 + j * 16;
        int rk = rbk + (lane >> 4);
        int ckk = (lane & 15) ^ (rk & 15);
        gload16(&kptr[(size_t)(kk0 + rk) * 4096 + ckk * 8], &kb[rbk * 128]);
        int rbv = wv * 16 + j * 64;
        int rv = rbv + (lane >> 2);
        int ckv = (lane & 3) ^ (rv & 3);
        gload16(&vptr[(size_t)rv * 2048 + kk0 + ckv * 8], &vb[rbv * 32]);
      }
    }
    // S = Q K^T (scores in log2 domain via QSCALE folded into q).
    // One K-frag read feeds BOTH row-halves (the traffic halving).
    f32x4 s[2][2] = {};
#pragma unroll
    for (int ks = 0; ks < 4; ks++) {
#pragma unroll
      for (int nt = 0; nt < 2; nt++) {
        bf16x8 bfr = *(const bf16x8*)&Kc[swz(nt * 16 + l16, ks * 4 + quad)];
        s[0][nt] = __builtin_amdgcn_mfma_f32_16x16x32_bf16(qf[0][ks], bfr, s[0][nt], 0, 0, 0);
        s[1][nt] = __builtin_amdgcn_mfma_f32_16x16x32_bf16(qf[1][ks], bfr, s[1][nt], 0, 0, 0);
      }
    }
    // fixed-base softmax: p = exp2(s); lane-local row-sum; P -> padded private buffer
#pragma unroll
    for (int hf = 0; hf < 2; hf++)
#pragma unroll
      for (int nt = 0; nt < 2; nt++)
#pragma unroll
        for (int r = 0; r < 4; r++) {
          float p = exp2f(s[hf][nt][r]);
          l[hf][r] += p;
          int row = wv * 32 + hf * 16 + quad * 4 + r;
          int col = nt * 16 + l16;
          Pb[row * 40 + col] = f2bf(p);
        }
    // cross-lane P round-trip: force all P ds_writes to retire before pf ds_reads
    FENCE_LDS();
    // O += P V  (Vc holds V^T: rows = d, cols = 32 keys; K=32 -> one MFMA per tile).
    // One V-frag read feeds BOTH row-halves.
    {
      bf16x8 pf0 = *(const bf16x8*)&Pb[(wv * 32 + l16) * 40 + quad * 8];
      bf16x8 pf1 = *(const bf16x8*)&Pb[(wv * 32 + 16 + l16) * 40 + quad * 8];
#pragma unroll
      for (int nt = 0; nt < 8; nt++) {
        bf16x8 vf = *(const bf16x8*)&Vc[swz32(nt * 16 + l16, quad)];
        o[0][nt] = __builtin_amdgcn_mfma_f32_16x16x32_bf16(pf0, vf, o[0][nt], 0, 0, 0);
        o[1][nt] = __builtin_amdgcn_mfma_f32_16x16x32_bf16(pf1, vf, o[1][nt], 0, 0, 0);
      }
    }
  }
  // epilogue: reduce l across the 16 col-lanes once, divide, store bf16
#pragma unroll
  for (int hf = 0; hf < 2; hf++)
#pragma unroll
    for (int r = 0; r < 4; r++)
#pragma unroll
      for (int off = 1; off < 16; off <<= 1) l[hf][r] += __shfl_xor(l[hf][r], off, 16);
  u16* obase = out + ((size_t)b * 2048 + q0) * 2048 + hh * 128;
#pragma unroll
  for (int hf = 0; hf < 2; hf++)
#pragma unroll
    for (int r = 0; r < 4; r++) {
      float inv = 1.0f / l[hf][r];
      int row = wv * 32 + hf * 16 + quad * 4 + r;
#pragma unroll
      for (int nt = 0; nt < 8; nt++)
        obase[(size_t)row * 2048 + nt * 16 + l16] = f2bf(o[hf][nt][r] * inv);
    }
}

// ---------------- launch ----------------
extern "C" void kernel_launch(void* const* d_in, const int* in_sizes, int n_in,
                              void* d_out, int out_size, void* d_ws, size_t ws_size,
                              hipStream_t stream) {
  const float* x    = (const float*)d_in[0];   // [4,2048,2048]
  const float* cosp = (const float*)d_in[1];   // [2048,128]
  const float* sinp = (const float*)d_in[2];   // [2048,128]
  const float* wqkv = (const float*)d_in[3];   // [6144,2048]
  const float* wout = (const float*)d_in[4];   // [2048,2048]
  float* outp = (float*)d_out;                 // [4,2048,2048] fp32

  u16* ws    = (u16*)d_ws;
  u16* xb    = ws;                     // 16,777,216 elems (dead after gemm_qkv; reused)
  u16* wqkvb = xb + 16777216;          // 12,582,912 (row-permuted q/k)
  u16* woutb = wqkvb + 12582912;       //  4,194,304
  u16* qkv   = woutb + 4194304;        // 33,554,432 (q,k only; row stride 4096)
  u16* vt    = qkv + 33554432;         // 16,777,216
  float2* cs = (float2*)(vt + 16777216); // 131,072 float2 = 1 MB
  u16* attn  = xb;                     // alias: xb dead after gemm_qkv

  prep<<<32896, 256, 0, stream>>>(x, wqkv, wout, cosp, sinp, xb, wqkvb, woutb, cs);
  gemm_qkv<<<768, 512, 0, stream>>>(xb, wqkvb, qkv, vt, cs);
  attn_fused<<<1024, 256, 0, stream>>>(qkv, vt, attn);
  gemm_out_k<<<256, 512, 0, stream>>>(attn, woutb, outp);
}

// Round 11
// 571.612 us; speedup vs baseline: 1.0538x; 1.0538x over previous
//
#include <hip/hip_runtime.h>
#include <cstdint>
#include <cstddef>

typedef unsigned short u16;
typedef __attribute__((ext_vector_type(8))) short bf16x8;   // 8 bf16 = 4 VGPRs
typedef __attribute__((ext_vector_type(4))) float f32x4;    // MFMA accumulator

#define DEVFN static __device__ __forceinline__

DEVFN u16 f2bf(float f) {
  unsigned u = __float_as_uint(f);
  unsigned r = (u + 0x7FFFu + ((u >> 16) & 1u)) >> 16;   // RTN-even
  return (u16)r;
}

// async global->LDS, 16B/lane. LDS dest = wave-uniform base + lane*16 (m104/m108).
DEVFN void gload16(const void* g, void* l) {
  __builtin_amdgcn_global_load_lds(
      (const __attribute__((address_space(1))) void*)g,
      (__attribute__((address_space(3))) void*)l, 16, 0, 0);
}

// counted waits + raw barrier (compiler memory fences keep LDS ops ordered)
#define WAITVM(n) asm volatile("s_waitcnt vmcnt(" #n ")" ::: "memory")
#define BARRIER() do { asm volatile("" ::: "memory"); \
                       __builtin_amdgcn_s_barrier();   \
                       asm volatile("" ::: "memory"); } while (0)
// Wave-internal LDS write->read fence (R9, rule #18): cross-lane P round-trip is
// invisible to LLVM's per-lane alias analysis.
#define FENCE_LDS() do { asm volatile("s_waitcnt lgkmcnt(0)" ::: "memory"); \
                         __builtin_amdgcn_sched_barrier(0); } while (0)

// ---------------- merged prep: converts + wqkv row-permute + cos/sin table ----------------
// wqkv q/k rows interleaved per head: d<64 -> 2d, d>=64 -> 2(d-64)+1  (QK^T invariant).
// cs[l*64+m] = (cos(l,m), sin(l,m))
__global__ void prep(const float* __restrict__ x, const float* __restrict__ wqkv,
                     const float* __restrict__ wout, const float* __restrict__ cosp,
                     const float* __restrict__ sinp, u16* __restrict__ xb,
                     u16* __restrict__ wqkvb, u16* __restrict__ woutb,
                     float2* __restrict__ cs) {
  constexpr int X4 = 4194304;      // x elems/4
  constexpr int W4 = 3145728;      // wqkv elems/4
  constexpr int O4 = 1048576;      // wout elems/4
  int i = blockIdx.x * blockDim.x + threadIdx.x;
  if (i < X4) {
    float4 v = ((const float4*)x)[i];
    unsigned long long w = (unsigned long long)f2bf(v.x)
        | ((unsigned long long)f2bf(v.y) << 16)
        | ((unsigned long long)f2bf(v.z) << 32)
        | ((unsigned long long)f2bf(v.w) << 48);
    *(unsigned long long*)(xb + (size_t)i * 4) = w;
  } else if (i < X4 + W4) {
    int j = i - X4;
    int base = j * 4;
    int e = base >> 11, col = base & 2047;
    int e2;
    if (e < 4096) {
      int part = e >> 11, loc = e & 2047;
      int h = loc >> 7, d = loc & 127;
      int d2 = (d < 64) ? 2 * d : 2 * (d - 64) + 1;
      e2 = part * 2048 + h * 128 + d2;
    } else {
      e2 = e;                      // v rows unpermuted
    }
    float4 v = *(const float4*)&wqkv[(size_t)base];
    unsigned long long w = (unsigned long long)f2bf(v.x)
        | ((unsigned long long)f2bf(v.y) << 16)
        | ((unsigned long long)f2bf(v.z) << 32)
        | ((unsigned long long)f2bf(v.w) << 48);
    *(unsigned long long*)(wqkvb + (size_t)e2 * 2048 + col) = w;
  } else if (i < X4 + W4 + O4) {
    int j = i - X4 - W4;
    float4 v = ((const float4*)wout)[j];
    unsigned long long w = (unsigned long long)f2bf(v.x)
        | ((unsigned long long)f2bf(v.y) << 16)
        | ((unsigned long long)f2bf(v.z) << 32)
        | ((unsigned long long)f2bf(v.w) << 48);
    *(unsigned long long*)(woutb + (size_t)j * 4) = w;
  } else {
    int k = i - X4 - W4 - O4;      // < 32768
    int ld4 = k * 4;
#pragma unroll
    for (int u = 0; u < 4; u++) {
      int ld = ld4 + u;
      int l = ld >> 6, d = ld & 63;
      cs[ld] = make_float2(cosp[(size_t)l * 128 + d], sinp[(size_t)l * 128 + d]);
    }
  }
}

// ========== 256x256 GEMM core, R13: R11 layout, ONE counted vmcnt per K-tile ==========
// BM=BN=256, BK=64, 512 thr = 8 waves (2M x 4N), wave output 128x64 = acc[8][4].
// LDS: A[2][256*64] + B[2][256*64] bf16 = 128 KB, dbuf by K-tile parity (R4/R11 verified).
// Evidence R10(8 waits)=312us < R12(4 waits)=216us < R11(2 waits)=203us: every vmcnt
// wait is a whole-CU stall point at 1 blk/CU; m201 waits once per K-tile at 62% util.
// R13 = R11 with ph2's WAITVM removed (A23 guarantee folded into ph1's deeper drain)
// and ph2's A23 reads hoisted BEFORE its barrier (overlap read latency, m201-style):
//   ph1: issue B(t+1)[4]; vmcnt(4) [drains ALL tile-t: 12->4]; BAR; read B+A01; 32 MFMA
//   ph2: read A23(t) [landed+visible since ph1 wait+bar]; issue A(t+1)[4]; BAR; 32 MFMA
// Steady-state 8 outstanding entering each tile; min staging lead = 1 full phase
// (A23: ph2(t-1) -> ph1(t) drain, ~2000cy >> HBM 900cy); never drains fresh loads.
// Peel: vmcnt(0), no staging. WAR: stage targets opposite-parity buffer; prior-parity
// reads retired >=2 barriers before any staging issue (lgkm before their MFMAs).
enum { M_F32OUT = 0, M_ROPE = 1, M_VT = 2 };

DEVFN bf16x8 rdfrag(const u16* buf, int row, int chunk) {
  return *(const bf16x8*)&buf[row * 64 + (((chunk ^ (row & 7)) & 7) << 3)];
}

// ph1 body: read B frags + A quads 0,1 (after barrier), 32 MFMA (compiler interleaves)
template <int MODE>
DEVFN void half_mfma0(const u16* Ac, const u16* Bc, int wm, int wn, int quad, int l16,
                      bf16x8 (&bfr)[4][2], f32x4 (&acc)[8][4]) {
#pragma unroll
  for (int j = 0; j < 4; j++)
#pragma unroll
    for (int kk = 0; kk < 2; kk++)
      bfr[j][kk] = rdfrag(Bc, wn * 64 + j * 16 + l16, kk * 4 + quad);
  bf16x8 af[2][2][2];        // [qi][i2][kk] rows 0..3
#pragma unroll
  for (int qi = 0; qi < 2; qi++)
#pragma unroll
    for (int i2 = 0; i2 < 2; i2++)
#pragma unroll
      for (int kk = 0; kk < 2; kk++)
        af[qi][i2][kk] = rdfrag(Ac, wm * 128 + (qi * 2 + i2) * 16 + l16, kk * 4 + quad);
  __builtin_amdgcn_s_setprio(1);
#pragma unroll
  for (int qi = 0; qi < 2; qi++)
#pragma unroll
    for (int kk = 0; kk < 2; kk++)
#pragma unroll
      for (int i2 = 0; i2 < 2; i2++)
#pragma unroll
        for (int j = 0; j < 4; j++) {
          int row = qi * 2 + i2;
          if (MODE == M_VT)
            acc[row][j] = __builtin_amdgcn_mfma_f32_16x16x32_bf16(
                bfr[j][kk], af[qi][i2][kk], acc[row][j], 0, 0, 0);
          else
            acc[row][j] = __builtin_amdgcn_mfma_f32_16x16x32_bf16(
                af[qi][i2][kk], bfr[j][kk], acc[row][j], 0, 0, 0);
        }
  __builtin_amdgcn_s_setprio(0);
}

// ph2 split: reads (issued before the barrier) and MFMA (after)
DEVFN void read_A23(const u16* Ac, int wm, int quad, int l16, bf16x8 (&af)[2][2][2]) {
#pragma unroll
  for (int qi = 0; qi < 2; qi++)
#pragma unroll
    for (int i2 = 0; i2 < 2; i2++)
#pragma unroll
      for (int kk = 0; kk < 2; kk++)
        af[qi][i2][kk] =
            rdfrag(Ac, wm * 128 + ((2 + qi) * 2 + i2) * 16 + l16, kk * 4 + quad);
}

template <int MODE>
DEVFN void mfma23(bf16x8 (&bfr)[4][2], bf16x8 (&af)[2][2][2], f32x4 (&acc)[8][4]) {
  __builtin_amdgcn_s_setprio(1);
#pragma unroll
  for (int qi = 0; qi < 2; qi++)
#pragma unroll
    for (int kk = 0; kk < 2; kk++)
#pragma unroll
      for (int i2 = 0; i2 < 2; i2++)
#pragma unroll
        for (int j = 0; j < 4; j++) {
          int row = (2 + qi) * 2 + i2;
          if (MODE == M_VT)
            acc[row][j] = __builtin_amdgcn_mfma_f32_16x16x32_bf16(
                bfr[j][kk], af[qi][i2][kk], acc[row][j], 0, 0, 0);
          else
            acc[row][j] = __builtin_amdgcn_mfma_f32_16x16x32_bf16(
                af[qi][i2][kk], bfr[j][kk], acc[row][j], 0, 0, 0);
        }
  __builtin_amdgcn_s_setprio(0);
}

template <int MODE>
DEVFN void gemm256_core(const u16* __restrict__ A, const u16* __restrict__ Bt,
                        void* __restrict__ Cv, const float2* __restrict__ cs,
                        int N, int m0, int n0, u16* As, u16* Bs) {
  int tid = threadIdx.x;
  int wv = tid >> 6, lane = tid & 63, quad = lane >> 4, l16 = lane & 15;
  int wm = wv >> 2, wn = wv & 3;

  // per-thread pre-swizzled global source pointers (advance by k elems per tile)
  const u16* pB[2][2];
  const u16* pA[4];
#pragma unroll
  for (int h = 0; h < 2; h++)
#pragma unroll
    for (int o = 0; o < 2; o++) {
      int r = h * 128 + o * 64 + wv * 8 + (lane >> 3);
      int ck = (lane & 7) ^ (r & 7);
      pB[h][o] = Bt + (size_t)(n0 + r) * 2048 + ck * 8;
    }
#pragma unroll
  for (int q = 0; q < 4; q++) {
    int rb = (wv < 4) ? (q * 32 + wv * 8) : (128 + q * 32 + (wv - 4) * 8);
    int r = rb + (lane >> 3);
    int ck = (lane & 7) ^ (r & 7);
    pA[q] = A + (size_t)(m0 + r) * 2048 + ck * 8;
  }

#define STAGE_B(h, buf, kk) do {                                    \
    int rb0_ = (h) * 128 + wv * 8;                                  \
    gload16(pB[h][0] + (kk), &(buf)[rb0_ * 64]);                    \
    gload16(pB[h][1] + (kk), &(buf)[(rb0_ + 64) * 64]); } while (0)
#define STAGE_A(q, buf, kk) do {                                    \
    int rb_ = ((wv < 4) ? ((q) * 32 + wv * 8)                       \
                        : (128 + (q) * 32 + (wv - 4) * 8));         \
    gload16(pA[q] + (kk), &(buf)[rb_ * 64]); } while (0)

  f32x4 acc[8][4] = {};
  bf16x8 bfr[4][2];
  bf16x8 af2[2][2][2];

  // prologue: stage tile 0 into buffer 0 (issue order = ledger order)
  STAGE_B(0, Bs, 0);
  STAGE_B(1, Bs, 0);
  STAGE_A(0, As, 0);
  STAGE_A(1, As, 0);
  STAGE_A(2, As, 0);
  STAGE_A(3, As, 0);

  for (int t = 0; t < 31; t++) {
    const u16* Ac = As + (t & 1) * 16384;
    const u16* Bc = Bs + (t & 1) * 16384;
    u16* An = As + ((t + 1) & 1) * 16384;
    u16* Bn = Bs + ((t + 1) & 1) * 16384;
    int kn = (t + 1) * 64;
    // ph1: the tile's ONLY vmcnt wait; reads after barrier
    STAGE_B(0, Bn, kn);
    STAGE_B(1, Bn, kn);
    WAITVM(4); BARRIER();                 // 12 -> 4: ALL of tile t landed; B(t+1) in flight
    half_mfma0<MODE>(Ac, Bc, wm, wn, quad, l16, bfr, acc);
    // ph2: A23 reads hoisted before the barrier (landed+visible since ph1's wait+bar)
    read_A23(Ac, wm, quad, l16, af2);
    STAGE_A(0, An, kn);
    STAGE_A(1, An, kn);
    STAGE_A(2, An, kn);
    STAGE_A(3, An, kn);
    BARRIER();                            // no vmcnt: only wave-sync for WAR spacing
    mfma23<MODE>(bfr, af2, acc);
  }
  {  // peeled last tile (parity 1), no staging
    const u16* Ac = As + 16384;
    const u16* Bc = Bs + 16384;
    WAITVM(0); BARRIER();
    half_mfma0<MODE>(Ac, Bc, wm, wn, quad, l16, bfr, acc);
    read_A23(Ac, wm, quad, l16, af2);
    mfma23<MODE>(bfr, af2, acc);
  }
#undef STAGE_B
#undef STAGE_A

  // ---- epilogue: C/D layout col = lane&15, row = quad*4 + reg (m89/m91 verified) ----
  if (MODE == M_F32OUT) {
    float* C = (float*)Cv;
#pragma unroll
    for (int i = 0; i < 8; i++)
#pragma unroll
      for (int r = 0; r < 4; r++) {
        size_t row = (size_t)(m0 + wm * 128 + i * 16 + quad * 4 + r);
#pragma unroll
        for (int j = 0; j < 4; j++)
          C[row * N + (n0 + wn * 64 + j * 16 + l16)] = acc[i][j][r];
      }
  } else if (MODE == M_ROPE) {
    constexpr float QSCALE = 1.4426950408889634f * 0.08838834764831845f;
    const float scale = (n0 >> 11) ? 1.0f : QSCALE;   // q gets log2e/sqrt(128)
    u16* C = (u16*)Cv;
#pragma unroll
    for (int i = 0; i < 8; i++)
#pragma unroll
      for (int r = 0; r < 4; r++) {
        int row = m0 + wm * 128 + i * 16 + quad * 4 + r;
        int l = row & 2047;
#pragma unroll
        for (int j = 0; j < 4; j++) {
          int col = n0 + wn * 64 + j * 16 + l16;
          int dm = (col & 127) >> 1;
          float2 csv = cs[l * 64 + dm];
          float v = acc[i][j][r];
          float pv = __shfl_xor(v, 1);                 // partner lane (col^1)
          float sg = (l16 & 1) ? csv.y : -csv.y;       // even: -sin, odd: +sin
          C[(size_t)row * 4096 + col] = f2bf((v * csv.x + pv * sg) * scale);
        }
      }
  } else {
    // VT: swapped operands -> acc holds C^T; row = v-channel, col = token. vt[bh][d][l].
    u16* vt = (u16*)Cv;
#pragma unroll
    for (int j = 0; j < 4; j++)
#pragma unroll
      for (int r = 0; r < 4; r++) {
        int vch = n0 + wn * 64 + j * 16 + quad * 4 + r;   // 0..2047
        int h = vch >> 7, d = vch & 127;
#pragma unroll
        for (int i = 0; i < 8; i++) {
          int token = m0 + wm * 128 + i * 16 + l16;
          int b = token >> 11, lloc = token & 2047;
          vt[((size_t)(b * 16 + h)) * 262144 + (size_t)d * 2048 + lloc] =
              f2bf(acc[i][j][r]);
        }
      }
  }
}

// Merged QKV GEMM: bx<16 -> RoPE epilogue into qkv (stride 4096); bx>=16 -> V^T.
// XCD y-striping: each XCD owns a 4-row stripe of M-tiles (A rows L2-resident).
__global__ __launch_bounds__(512, 2) void gemm_qkv(const u16* __restrict__ xb,
                                                   const u16* __restrict__ wqkvb,
                                                   u16* __restrict__ qkvo,
                                                   u16* __restrict__ vto,
                                                   const float2* __restrict__ cs) {
  __shared__ u16 As[32768];
  __shared__ u16 Bs[32768];
  int id = blockIdx.x;
  int xcd = id & 7, sub = id >> 3;      // sub 0..95
  int bx = sub % 24, by = xcd * 4 + sub / 24;
  if (bx < 16)
    gemm256_core<M_ROPE>(xb, wqkvb, qkvo, cs, 0, by * 256, bx * 256, As, Bs);
  else
    gemm256_core<M_VT>(xb, wqkvb + (size_t)4096 * 2048, vto, nullptr, 0,
                       by * 256, (bx - 16) * 256, As, Bs);
}

__global__ __launch_bounds__(512, 2) void gemm_out_k(const u16* __restrict__ A,
                                                     const u16* __restrict__ Bt,
                                                     float* __restrict__ C) {
  __shared__ u16 As[32768];
  __shared__ u16 Bs[32768];
  int id = blockIdx.x;
  int xcd = id & 7, sub = id >> 3;      // sub 0..31
  int bx = sub % 8, by = xcd * 4 + sub / 8;
  gemm256_core<M_F32OUT>(A, Bt, C, nullptr, 2048, by * 256, bx * 256, As, Bs);
}

// ---------------- fused flash attention (fixed-base softmax, no online max) ----------------
// R9 (verified): 256 thr / 4 waves / 32 q-rows per wave (each K/V fragment read feeds
// TWO row-tiles), KVBLK=32, double-buffered K (2x8KB) + V (2x8KB) + padded P
// (128 x 40 = 10KB) = 43KB LDS -> 3 blocks/CU, 12 waves/CU. FENCE_LDS between the
// P-write loop and pf reads (R8 failure: compiler hoisted the cross-lane ds_read).
DEVFN int swz(int row, int chunk)   { return row * 128 + ((chunk ^ (row & 15)) << 3); } // 256B rows
DEVFN int swz32(int row, int chunk) { return row * 32  + (((chunk ^ (row & 3)) & 3) << 3); } // 64B rows

__global__ __launch_bounds__(256, 3) void attn_fused(const u16* __restrict__ qkv,
                                                     const u16* __restrict__ vt,
                                                     u16* __restrict__ out) {
  // S layout (u16 units): [0,4096)=Kb0 [4096,8192)=Kb1
  //                       [8192,12288)=Vb0 [12288,16384)=Vb1
  //                       [16384,21504)=P (128 rows x 40 elems, 80B stride: bank-spread)
  __shared__ u16 S[21504];                     // 43008 B
  u16* const Pb = S + 16384;
  int tid = threadIdx.x;
  int wv = tid >> 6, lane = tid & 63, quad = lane >> 4, l16 = lane & 15;
  int id = blockIdx.x;
  int xcd = id & 7, sub = id >> 3;             // sub 0..127
  int bh = ((sub >> 4) << 3) | xcd;            // 8 bh per XCD, all 16 qtiles local
  int qt = sub & 15;
  int b = bh >> 4, hh = bh & 15;
  const u16* qptr = qkv + (size_t)b * 2048 * 4096 + hh * 128;
  const u16* kptr = qptr + 2048;
  const u16* vptr = vt + (size_t)bh * 262144;
  int q0 = qt * 128;

  // ---- Q staging: 128 rows x 256B through S[0..16384), then pull to regs ----
#pragma unroll
  for (int j = 0; j < 8; j++) {
    int rb = wv * 4 + j * 16;
    int r = rb + (lane >> 4);
    int ck = (lane & 15) ^ (r & 15);
    gload16(&qptr[(size_t)(q0 + r) * 4096 + ck * 8], &S[rb * 128]);
  }
  __syncthreads();
  bf16x8 qf[2][4];
#pragma unroll
  for (int hf = 0; hf < 2; hf++)
#pragma unroll
    for (int ks = 0; ks < 4; ks++)
      qf[hf][ks] = *(const bf16x8*)&S[swz(wv * 32 + hf * 16 + l16, ks * 4 + quad)];
  __syncthreads();                             // qf reads done before kt=0 staging

  f32x4 o[2][8] = {};
  float l[2][4] = {{0.f, 0.f, 0.f, 0.f}, {0.f, 0.f, 0.f, 0.f}};

  // prologue: stage kt=0 into Kb0/Vb0 (K: 32 rows x 256B; V^T: 128 rows x 64B)
#pragma unroll
  for (int j = 0; j < 2; j++) {
    int rbk = wv * 4 + j * 16;
    int rk = rbk + (lane >> 4);
    int ckk = (lane & 15) ^ (rk & 15);
    gload16(&kptr[(size_t)rk * 4096 + ckk * 8], &S[rbk * 128]);
    int rbv = wv * 16 + j * 64;
    int rv = rbv + (lane >> 2);
    int ckv = (lane & 3) ^ (rv & 3);
    gload16(&vptr[(size_t)rv * 2048 + ckv * 8], &S[8192 + rbv * 32]);
  }

  for (int kt = 0; kt < 64; kt++) {
    int cur = kt & 1;
    const u16* Kc = S + cur * 4096;
    const u16* Vc = S + 8192 + cur * 4096;
    __syncthreads();   // auto vmcnt(0): drains cur-tile loads (1 iter old) + prior reads
    if (kt < 63) {     // prefetch kt+1 into the other buffer set
      int kk0 = (kt + 1) * 32;
      u16* kb = S + (cur ^ 1) * 4096;
      u16* vb = S + 8192 + (cur ^ 1) * 4096;
#pragma unroll
      for (int j = 0; j < 2; j++) {
        int rbk = wv * 4 + j * 16;
        int rk = rbk + (lane >> 4);
        int ckk = (lane & 15) ^ (rk & 15);
        gload16(&kptr[(size_t)(kk0 + rk) * 4096 + ckk * 8], &kb[rbk * 128]);
        int rbv = wv * 16 + j * 64;
        int rv = rbv + (lane >> 2);
        int ckv = (lane & 3) ^ (rv & 3);
        gload16(&vptr[(size_t)rv * 2048 + kk0 + ckv * 8], &vb[rbv * 32]);
      }
    }
    // S = Q K^T (scores in log2 domain via QSCALE folded into q).
    // One K-frag read feeds BOTH row-halves (the traffic halving).
    f32x4 s[2][2] = {};
#pragma unroll
    for (int ks = 0; ks < 4; ks++) {
#pragma unroll
      for (int nt = 0; nt < 2; nt++) {
        bf16x8 bfr = *(const bf16x8*)&Kc[swz(nt * 16 + l16, ks * 4 + quad)];
        s[0][nt] = __builtin_amdgcn_mfma_f32_16x16x32_bf16(qf[0][ks], bfr, s[0][nt], 0, 0, 0);
        s[1][nt] = __builtin_amdgcn_mfma_f32_16x16x32_bf16(qf[1][ks], bfr, s[1][nt], 0, 0, 0);
      }
    }
    // fixed-base softmax: p = exp2(s); lane-local row-sum; P -> padded private buffer
#pragma unroll
    for (int hf = 0; hf < 2; hf++)
#pragma unroll
      for (int nt = 0; nt < 2; nt++)
#pragma unroll
        for (int r = 0; r < 4; r++) {
          float p = exp2f(s[hf][nt][r]);
          l[hf][r] += p;
          int row = wv * 32 + hf * 16 + quad * 4 + r;
          int col = nt * 16 + l16;
          Pb[row * 40 + col] = f2bf(p);
        }
    // cross-lane P round-trip: force all P ds_writes to retire before pf ds_reads
    FENCE_LDS();
    // O += P V  (Vc holds V^T: rows = d, cols = 32 keys; K=32 -> one MFMA per tile).
    // One V-frag read feeds BOTH row-halves.
    {
      bf16x8 pf0 = *(const bf16x8*)&Pb[(wv * 32 + l16) * 40 + quad * 8];
      bf16x8 pf1 = *(const bf16x8*)&Pb[(wv * 32 + 16 + l16) * 40 + quad * 8];
#pragma unroll
      for (int nt = 0; nt < 8; nt++) {
        bf16x8 vf = *(const bf16x8*)&Vc[swz32(nt * 16 + l16, quad)];
        o[0][nt] = __builtin_amdgcn_mfma_f32_16x16x32_bf16(pf0, vf, o[0][nt], 0, 0, 0);
        o[1][nt] = __builtin_amdgcn_mfma_f32_16x16x32_bf16(pf1, vf, o[1][nt], 0, 0, 0);
      }
    }
  }
  // epilogue: reduce l across the 16 col-lanes once, divide, store bf16
#pragma unroll
  for (int hf = 0; hf < 2; hf++)
#pragma unroll
    for (int r = 0; r < 4; r++)
#pragma unroll
      for (int off = 1; off < 16; off <<= 1) l[hf][r] += __shfl_xor(l[hf][r], off, 16);
  u16* obase = out + ((size_t)b * 2048 + q0) * 2048 + hh * 128;
#pragma unroll
  for (int hf = 0; hf < 2; hf++)
#pragma unroll
    for (int r = 0; r < 4; r++) {
      float inv = 1.0f / l[hf][r];
      int row = wv * 32 + hf * 16 + quad * 4 + r;
#pragma unroll
      for (int nt = 0; nt < 8; nt++)
        obase[(size_t)row * 2048 + nt * 16 + l16] = f2bf(o[hf][nt][r] * inv);
    }
}

// ---------------- launch ----------------
extern "C" void kernel_launch(void* const* d_in, const int* in_sizes, int n_in,
                              void* d_out, int out_size, void* d_ws, size_t ws_size,
                              hipStream_t stream) {
  const float* x    = (const float*)d_in[0];   // [4,2048,2048]
  const float* cosp = (const float*)d_in[1];   // [2048,128]
  const float* sinp = (const float*)d_in[2];   // [2048,128]
  const float* wqkv = (const float*)d_in[3];   // [6144,2048]
  const float* wout = (const float*)d_in[4];   // [2048,2048]
  float* outp = (float*)d_out;                 // [4,2048,2048] fp32

  u16* ws    = (u16*)d_ws;
  u16* xb    = ws;                     // 16,777,216 elems (dead after gemm_qkv; reused)
  u16* wqkvb = xb + 16777216;          // 12,582,912 (row-permuted q/k)
  u16* woutb = wqkvb + 12582912;       //  4,194,304
  u16* qkv   = woutb + 4194304;        // 33,554,432 (q,k only; row stride 4096)
  u16* vt    = qkv + 33554432;         // 16,777,216
  float2* cs = (float2*)(vt + 16777216); // 131,072 float2 = 1 MB
  u16* attn  = xb;                     // alias: xb dead after gemm_qkv

  prep<<<32896, 256, 0, stream>>>(x, wqkv, wout, cosp, sinp, xb, wqkvb, woutb, cs);
  gemm_qkv<<<768, 512, 0, stream>>>(xb, wqkvb, qkv, vt, cs);
  attn_fused<<<1024, 256, 0, stream>>>(qkv, vt, attn);
  gemm_out_k<<<256, 512, 0, stream>>>(attn, woutb, outp);
}

// Round 12
// 569.667 us; speedup vs baseline: 1.0574x; 1.0034x over previous
//
#include <hip/hip_runtime.h>
#include <cstdint>
#include <cstddef>

typedef unsigned short u16;
typedef unsigned long long u64;
typedef __attribute__((ext_vector_type(8))) short bf16x8;   // 8 bf16 = 4 VGPRs
typedef __attribute__((ext_vector_type(4))) float f32x4;    // MFMA accumulator

#define DEVFN static __device__ __forceinline__

DEVFN u16 f2bf(float f) {
  unsigned u = __float_as_uint(f);
  unsigned r = (u + 0x7FFFu + ((u >> 16) & 1u)) >> 16;   // RTN-even
  return (u16)r;
}

// async global->LDS, 16B/lane. LDS dest = wave-uniform base + lane*16 (m104/m108).
DEVFN void gload16(const void* g, void* l) {
  __builtin_amdgcn_global_load_lds(
      (const __attribute__((address_space(1))) void*)g,
      (__attribute__((address_space(3))) void*)l, 16, 0, 0);
}

// counted waits + raw barrier (compiler memory fences keep LDS ops ordered)
#define WAITVM(n) asm volatile("s_waitcnt vmcnt(" #n ")" ::: "memory")
#define BARRIER() do { asm volatile("" ::: "memory"); \
                       __builtin_amdgcn_s_barrier();   \
                       asm volatile("" ::: "memory"); } while (0)
// Wave-internal LDS write->read fence (R9, rule #18): cross-lane P round-trip is
// invisible to LLVM's per-lane alias analysis.
#define FENCE_LDS() do { asm volatile("s_waitcnt lgkmcnt(0)" ::: "memory"); \
                         __builtin_amdgcn_sched_barrier(0); } while (0)

// ---------------- merged prep: converts + wqkv row-permute + cos/sin table ----------------
// wqkv q/k rows interleaved per head: d<64 -> 2d, d>=64 -> 2(d-64)+1  (QK^T invariant).
// cs[l*64+m] = (cos(l,m), sin(l,m))
__global__ void prep(const float* __restrict__ x, const float* __restrict__ wqkv,
                     const float* __restrict__ wout, const float* __restrict__ cosp,
                     const float* __restrict__ sinp, u16* __restrict__ xb,
                     u16* __restrict__ wqkvb, u16* __restrict__ woutb,
                     float2* __restrict__ cs) {
  constexpr int X4 = 4194304;      // x elems/4
  constexpr int W4 = 3145728;      // wqkv elems/4
  constexpr int O4 = 1048576;      // wout elems/4
  int i = blockIdx.x * blockDim.x + threadIdx.x;
  if (i < X4) {
    float4 v = ((const float4*)x)[i];
    unsigned long long w = (unsigned long long)f2bf(v.x)
        | ((unsigned long long)f2bf(v.y) << 16)
        | ((unsigned long long)f2bf(v.z) << 32)
        | ((unsigned long long)f2bf(v.w) << 48);
    *(unsigned long long*)(xb + (size_t)i * 4) = w;
  } else if (i < X4 + W4) {
    int j = i - X4;
    int base = j * 4;
    int e = base >> 11, col = base & 2047;
    int e2;
    if (e < 4096) {
      int part = e >> 11, loc = e & 2047;
      int h = loc >> 7, d = loc & 127;
      int d2 = (d < 64) ? 2 * d : 2 * (d - 64) + 1;
      e2 = part * 2048 + h * 128 + d2;
    } else {
      e2 = e;                      // v rows unpermuted
    }
    float4 v = *(const float4*)&wqkv[(size_t)base];
    unsigned long long w = (unsigned long long)f2bf(v.x)
        | ((unsigned long long)f2bf(v.y) << 16)
        | ((unsigned long long)f2bf(v.z) << 32)
        | ((unsigned long long)f2bf(v.w) << 48);
    *(unsigned long long*)(wqkvb + (size_t)e2 * 2048 + col) = w;
  } else if (i < X4 + W4 + O4) {
    int j = i - X4 - W4;
    float4 v = ((const float4*)wout)[j];
    unsigned long long w = (unsigned long long)f2bf(v.x)
        | ((unsigned long long)f2bf(v.y) << 16)
        | ((unsigned long long)f2bf(v.z) << 32)
        | ((unsigned long long)f2bf(v.w) << 48);
    *(unsigned long long*)(woutb + (size_t)j * 4) = w;
  } else {
    int k = i - X4 - W4 - O4;      // < 32768
    int ld4 = k * 4;
#pragma unroll
    for (int u = 0; u < 4; u++) {
      int ld = ld4 + u;
      int l = ld >> 6, d = ld & 63;
      cs[ld] = make_float2(cosp[(size_t)l * 128 + d], sinp[(size_t)l * 128 + d]);
    }
  }
}

// ========== 256x256 GEMM core, R13 (kept): R11 layout, ONE counted vmcnt per K-tile ==========
// Schedule verified at 202-205us (R11/R13 ~equal; wait-count sweep saturated: 8w=312,
// 4w=216, 2w=203, 1w=205). See R13 comments; unchanged this round.
enum { M_F32OUT = 0, M_ROPE = 1, M_VT = 2 };

DEVFN bf16x8 rdfrag(const u16* buf, int row, int chunk) {
  return *(const bf16x8*)&buf[row * 64 + (((chunk ^ (row & 7)) & 7) << 3)];
}

// ph1 body: read B frags + A quads 0,1 (after barrier), 32 MFMA (compiler interleaves)
template <int MODE>
DEVFN void half_mfma0(const u16* Ac, const u16* Bc, int wm, int wn, int quad, int l16,
                      bf16x8 (&bfr)[4][2], f32x4 (&acc)[8][4]) {
#pragma unroll
  for (int j = 0; j < 4; j++)
#pragma unroll
    for (int kk = 0; kk < 2; kk++)
      bfr[j][kk] = rdfrag(Bc, wn * 64 + j * 16 + l16, kk * 4 + quad);
  bf16x8 af[2][2][2];        // [qi][i2][kk] rows 0..3
#pragma unroll
  for (int qi = 0; qi < 2; qi++)
#pragma unroll
    for (int i2 = 0; i2 < 2; i2++)
#pragma unroll
      for (int kk = 0; kk < 2; kk++)
        af[qi][i2][kk] = rdfrag(Ac, wm * 128 + (qi * 2 + i2) * 16 + l16, kk * 4 + quad);
  __builtin_amdgcn_s_setprio(1);
#pragma unroll
  for (int qi = 0; qi < 2; qi++)
#pragma unroll
    for (int kk = 0; kk < 2; kk++)
#pragma unroll
      for (int i2 = 0; i2 < 2; i2++)
#pragma unroll
        for (int j = 0; j < 4; j++) {
          int row = qi * 2 + i2;
          if (MODE == M_VT)
            acc[row][j] = __builtin_amdgcn_mfma_f32_16x16x32_bf16(
                bfr[j][kk], af[qi][i2][kk], acc[row][j], 0, 0, 0);
          else
            acc[row][j] = __builtin_amdgcn_mfma_f32_16x16x32_bf16(
                af[qi][i2][kk], bfr[j][kk], acc[row][j], 0, 0, 0);
        }
  __builtin_amdgcn_s_setprio(0);
}

// ph2 split: reads (issued before the barrier) and MFMA (after)
DEVFN void read_A23(const u16* Ac, int wm, int quad, int l16, bf16x8 (&af)[2][2][2]) {
#pragma unroll
  for (int qi = 0; qi < 2; qi++)
#pragma unroll
    for (int i2 = 0; i2 < 2; i2++)
#pragma unroll
      for (int kk = 0; kk < 2; kk++)
        af[qi][i2][kk] =
            rdfrag(Ac, wm * 128 + ((2 + qi) * 2 + i2) * 16 + l16, kk * 4 + quad);
}

template <int MODE>
DEVFN void mfma23(bf16x8 (&bfr)[4][2], bf16x8 (&af)[2][2][2], f32x4 (&acc)[8][4]) {
  __builtin_amdgcn_s_setprio(1);
#pragma unroll
  for (int qi = 0; qi < 2; qi++)
#pragma unroll
    for (int kk = 0; kk < 2; kk++)
#pragma unroll
      for (int i2 = 0; i2 < 2; i2++)
#pragma unroll
        for (int j = 0; j < 4; j++) {
          int row = (2 + qi) * 2 + i2;
          if (MODE == M_VT)
            acc[row][j] = __builtin_amdgcn_mfma_f32_16x16x32_bf16(
                bfr[j][kk], af[qi][i2][kk], acc[row][j], 0, 0, 0);
          else
            acc[row][j] = __builtin_amdgcn_mfma_f32_16x16x32_bf16(
                af[qi][i2][kk], bfr[j][kk], acc[row][j], 0, 0, 0);
        }
  __builtin_amdgcn_s_setprio(0);
}

template <int MODE>
DEVFN void gemm256_core(const u16* __restrict__ A, const u16* __restrict__ Bt,
                        void* __restrict__ Cv, const float2* __restrict__ cs,
                        int N, int m0, int n0, u16* As, u16* Bs) {
  int tid = threadIdx.x;
  int wv = tid >> 6, lane = tid & 63, quad = lane >> 4, l16 = lane & 15;
  int wm = wv >> 2, wn = wv & 3;

  // per-thread pre-swizzled global source pointers (advance by k elems per tile)
  const u16* pB[2][2];
  const u16* pA[4];
#pragma unroll
  for (int h = 0; h < 2; h++)
#pragma unroll
    for (int o = 0; o < 2; o++) {
      int r = h * 128 + o * 64 + wv * 8 + (lane >> 3);
      int ck = (lane & 7) ^ (r & 7);
      pB[h][o] = Bt + (size_t)(n0 + r) * 2048 + ck * 8;
    }
#pragma unroll
  for (int q = 0; q < 4; q++) {
    int rb = (wv < 4) ? (q * 32 + wv * 8) : (128 + q * 32 + (wv - 4) * 8);
    int r = rb + (lane >> 3);
    int ck = (lane & 7) ^ (r & 7);
    pA[q] = A + (size_t)(m0 + r) * 2048 + ck * 8;
  }

#define STAGE_B(h, buf, kk) do {                                    \
    int rb0_ = (h) * 128 + wv * 8;                                  \
    gload16(pB[h][0] + (kk), &(buf)[rb0_ * 64]);                    \
    gload16(pB[h][1] + (kk), &(buf)[(rb0_ + 64) * 64]); } while (0)
#define STAGE_A(q, buf, kk) do {                                    \
    int rb_ = ((wv < 4) ? ((q) * 32 + wv * 8)                       \
                        : (128 + (q) * 32 + (wv - 4) * 8));         \
    gload16(pA[q] + (kk), &(buf)[rb_ * 64]); } while (0)

  f32x4 acc[8][4] = {};
  bf16x8 bfr[4][2];
  bf16x8 af2[2][2][2];

  // prologue: stage tile 0 into buffer 0 (issue order = ledger order)
  STAGE_B(0, Bs, 0);
  STAGE_B(1, Bs, 0);
  STAGE_A(0, As, 0);
  STAGE_A(1, As, 0);
  STAGE_A(2, As, 0);
  STAGE_A(3, As, 0);

  for (int t = 0; t < 31; t++) {
    const u16* Ac = As + (t & 1) * 16384;
    const u16* Bc = Bs + (t & 1) * 16384;
    u16* An = As + ((t + 1) & 1) * 16384;
    u16* Bn = Bs + ((t + 1) & 1) * 16384;
    int kn = (t + 1) * 64;
    // ph1: the tile's ONLY vmcnt wait; reads after barrier
    STAGE_B(0, Bn, kn);
    STAGE_B(1, Bn, kn);
    WAITVM(4); BARRIER();                 // 12 -> 4: ALL of tile t landed; B(t+1) in flight
    half_mfma0<MODE>(Ac, Bc, wm, wn, quad, l16, bfr, acc);
    // ph2: A23 reads hoisted before the barrier (landed+visible since ph1's wait+bar)
    read_A23(Ac, wm, quad, l16, af2);
    STAGE_A(0, An, kn);
    STAGE_A(1, An, kn);
    STAGE_A(2, An, kn);
    STAGE_A(3, An, kn);
    BARRIER();                            // no vmcnt: only wave-sync for WAR spacing
    mfma23<MODE>(bfr, af2, acc);
  }
  {  // peeled last tile (parity 1), no staging
    const u16* Ac = As + 16384;
    const u16* Bc = Bs + 16384;
    WAITVM(0); BARRIER();
    half_mfma0<MODE>(Ac, Bc, wm, wn, quad, l16, bfr, acc);
    read_A23(Ac, wm, quad, l16, af2);
    mfma23<MODE>(bfr, af2, acc);
  }
#undef STAGE_B
#undef STAGE_A

  // ---- epilogue: C/D layout col = lane&15, row = quad*4 + reg (m89/m91 verified) ----
  if (MODE == M_F32OUT) {
    float* C = (float*)Cv;
#pragma unroll
    for (int i = 0; i < 8; i++)
#pragma unroll
      for (int r = 0; r < 4; r++) {
        size_t row = (size_t)(m0 + wm * 128 + i * 16 + quad * 4 + r);
#pragma unroll
        for (int j = 0; j < 4; j++)
          C[row * N + (n0 + wn * 64 + j * 16 + l16)] = acc[i][j][r];
      }
  } else if (MODE == M_ROPE) {
    constexpr float QSCALE = 1.4426950408889634f * 0.08838834764831845f;
    const float scale = (n0 >> 11) ? 1.0f : QSCALE;   // q gets log2e/sqrt(128)
    u16* C = (u16*)Cv;
#pragma unroll
    for (int i = 0; i < 8; i++)
#pragma unroll
      for (int r = 0; r < 4; r++) {
        int row = m0 + wm * 128 + i * 16 + quad * 4 + r;
        int l = row & 2047;
#pragma unroll
        for (int j = 0; j < 4; j++) {
          int col = n0 + wn * 64 + j * 16 + l16;
          int dm = (col & 127) >> 1;
          float2 csv = cs[l * 64 + dm];
          float v = acc[i][j][r];
          float pv = __shfl_xor(v, 1);                 // partner lane (col^1)
          float sg = (l16 & 1) ? csv.y : -csv.y;       // even: -sin, odd: +sin
          C[(size_t)row * 4096 + col] = f2bf((v * csv.x + pv * sg) * scale);
        }
      }
  } else {
    // VT: swapped operands -> acc holds C^T; row = v-channel, col = token. vt[bh][d][l].
    u16* vt = (u16*)Cv;
#pragma unroll
    for (int j = 0; j < 4; j++)
#pragma unroll
      for (int r = 0; r < 4; r++) {
        int vch = n0 + wn * 64 + j * 16 + quad * 4 + r;   // 0..2047
        int h = vch >> 7, d = vch & 127;
#pragma unroll
        for (int i = 0; i < 8; i++) {
          int token = m0 + wm * 128 + i * 16 + l16;
          int b = token >> 11, lloc = token & 2047;
          vt[((size_t)(b * 16 + h)) * 262144 + (size_t)d * 2048 + lloc] =
              f2bf(acc[i][j][r]);
        }
      }
  }
}

// Merged QKV GEMM: bx<16 -> RoPE epilogue into qkv (stride 4096); bx>=16 -> V^T.
// R14: by-INNER block order per XCD (by = xcd*4 + sub%4, bx = sub/4). The 32
// co-resident blocks per XCD now cover 4 A-tiles x 8 B-panels (12 MB working set,
// each B-panel shared by 4 blocks) vs bx-inner's 24 B-panels (26 MB >> 4MB L2).
__global__ __launch_bounds__(512, 2) void gemm_qkv(const u16* __restrict__ xb,
                                                   const u16* __restrict__ wqkvb,
                                                   u16* __restrict__ qkvo,
                                                   u16* __restrict__ vto,
                                                   const float2* __restrict__ cs) {
  __shared__ u16 As[32768];
  __shared__ u16 Bs[32768];
  int id = blockIdx.x;
  int xcd = id & 7, sub = id >> 3;      // sub 0..95
  int bx = sub >> 2, by = xcd * 4 + (sub & 3);
  if (bx < 16)
    gemm256_core<M_ROPE>(xb, wqkvb, qkvo, cs, 0, by * 256, bx * 256, As, Bs);
  else
    gemm256_core<M_VT>(xb, wqkvb + (size_t)4096 * 2048, vto, nullptr, 0,
                       by * 256, (bx - 16) * 256, As, Bs);
}

__global__ __launch_bounds__(512, 2) void gemm_out_k(const u16* __restrict__ A,
                                                     const u16* __restrict__ Bt,
                                                     float* __restrict__ C) {
  __shared__ u16 As[32768];
  __shared__ u16 Bs[32768];
  int id = blockIdx.x;
  int xcd = id & 7, sub = id >> 3;      // sub 0..31
  int bx = sub % 8, by = xcd * 4 + sub / 8;
  gemm256_core<M_F32OUT>(A, Bt, C, nullptr, 2048, by * 256, bx * 256, As, Bs);
}

// ---------------- fused flash attention (fixed-base softmax, no online max) ----------------
// R14 = R9 structure with SWAPPED QK^T: s = mfma(K_frag, Q_frag) -> C row=key, col=query
// (same verified mapping as the GEMM's VT mode: mfma(X,Y) => row=X-row, col=Y-row).
// Lane now holds, per query l16, keys quad*4+r CONTIGUOUS -> P store becomes 4x packed
// ds_write_b64 (was 16x ds_write_b16): LDS demand -22%/wave-kt. P READ side (pf), PV,
// O layout are byte-identical to R9 (verified). lsum: per-lane-query partial ->
// quad-reduce shfl_xor(16,32); epilogue pulls 1/l via __shfl(lsum, quad*4+r, 16).
// b64 write banks: 20*l16 mod 32 -> 2-way alias (free, m136). FENCE_LDS kept (cross-quad
// write->read still invisible to per-lane alias analysis).
DEVFN int swz(int row, int chunk)   { return row * 128 + ((chunk ^ (row & 15)) << 3); } // 256B rows
DEVFN int swz32(int row, int chunk) { return row * 32  + (((chunk ^ (row & 3)) & 3) << 3); } // 64B rows

__global__ __launch_bounds__(256, 3) void attn_fused(const u16* __restrict__ qkv,
                                                     const u16* __restrict__ vt,
                                                     u16* __restrict__ out) {
  // S layout (u16 units): [0,4096)=Kb0 [4096,8192)=Kb1
  //                       [8192,12288)=Vb0 [12288,16384)=Vb1
  //                       [16384,21504)=P (128 rows x 40 elems, 80B stride: bank-spread)
  __shared__ u16 S[21504];                     // 43008 B
  u16* const Pb = S + 16384;
  int tid = threadIdx.x;
  int wv = tid >> 6, lane = tid & 63, quad = lane >> 4, l16 = lane & 15;
  int id = blockIdx.x;
  int xcd = id & 7, sub = id >> 3;             // sub 0..127
  int bh = ((sub >> 4) << 3) | xcd;            // 8 bh per XCD, all 16 qtiles local
  int qt = sub & 15;
  int b = bh >> 4, hh = bh & 15;
  const u16* qptr = qkv + (size_t)b * 2048 * 4096 + hh * 128;
  const u16* kptr = qptr + 2048;
  const u16* vptr = vt + (size_t)bh * 262144;
  int q0 = qt * 128;

  // ---- Q staging: 128 rows x 256B through S[0..16384), then pull to regs ----
#pragma unroll
  for (int j = 0; j < 8; j++) {
    int rb = wv * 4 + j * 16;
    int r = rb + (lane >> 4);
    int ck = (lane & 15) ^ (r & 15);
    gload16(&qptr[(size_t)(q0 + r) * 4096 + ck * 8], &S[rb * 128]);
  }
  __syncthreads();
  bf16x8 qf[2][4];
#pragma unroll
  for (int hf = 0; hf < 2; hf++)
#pragma unroll
    for (int ks = 0; ks < 4; ks++)
      qf[hf][ks] = *(const bf16x8*)&S[swz(wv * 32 + hf * 16 + l16, ks * 4 + quad)];
  __syncthreads();                             // qf reads done before kt=0 staging

  f32x4 o[2][8] = {};
  float lsum[2] = {0.f, 0.f};

  // prologue: stage kt=0 into Kb0/Vb0 (K: 32 rows x 256B; V^T: 128 rows x 64B)
#pragma unroll
  for (int j = 0; j < 2; j++) {
    int rbk = wv * 4 + j * 16;
    int rk = rbk + (lane >> 4);
    int ckk = (lane & 15) ^ (rk & 15);
    gload16(&kptr[(size_t)rk * 4096 + ckk * 8], &S[rbk * 128]);
    int rbv = wv * 16 + j * 64;
    int rv = rbv + (lane >> 2);
    int ckv = (lane & 3) ^ (rv & 3);
    gload16(&vptr[(size_t)rv * 2048 + ckv * 8], &S[8192 + rbv * 32]);
  }

  for (int kt = 0; kt < 64; kt++) {
    int cur = kt & 1;
    const u16* Kc = S + cur * 4096;
    const u16* Vc = S + 8192 + cur * 4096;
    __syncthreads();   // auto vmcnt(0): drains cur-tile loads (1 iter old) + prior reads
    if (kt < 63) {     // prefetch kt+1 into the other buffer set
      int kk0 = (kt + 1) * 32;
      u16* kb = S + (cur ^ 1) * 4096;
      u16* vb = S + 8192 + (cur ^ 1) * 4096;
#pragma unroll
      for (int j = 0; j < 2; j++) {
        int rbk = wv * 4 + j * 16;
        int rk = rbk + (lane >> 4);
        int ckk = (lane & 15) ^ (rk & 15);
        gload16(&kptr[(size_t)(kk0 + rk) * 4096 + ckk * 8], &kb[rbk * 128]);
        int rbv = wv * 16 + j * 64;
        int rv = rbv + (lane >> 2);
        int ckv = (lane & 3) ^ (rv & 3);
        gload16(&vptr[(size_t)rv * 2048 + kk0 + ckv * 8], &vb[rbv * 32]);
      }
    }
    // S^T = K Q^T via swapped operands (scores in log2 domain via QSCALE folded into q).
    // Lane holds col=query(l16), rows=keys nt*16+quad*4+r. One K-frag read feeds both
    // query-halves (traffic sharing preserved).
    f32x4 s[2][2] = {};   // [hf: query-16-block][nt: key-16-block]
#pragma unroll
    for (int ks = 0; ks < 4; ks++) {
#pragma unroll
      for (int nt = 0; nt < 2; nt++) {
        bf16x8 kfr = *(const bf16x8*)&Kc[swz(nt * 16 + l16, ks * 4 + quad)];
        s[0][nt] = __builtin_amdgcn_mfma_f32_16x16x32_bf16(kfr, qf[0][ks], s[0][nt], 0, 0, 0);
        s[1][nt] = __builtin_amdgcn_mfma_f32_16x16x32_bf16(kfr, qf[1][ks], s[1][nt], 0, 0, 0);
      }
    }
    // fixed-base softmax: p = exp2(s); per-lane-query row-sum; P stored as packed b64
    // (4 contiguous keys quad*4+0..3 per lane) into P[query][key] (stride 40 u16).
#pragma unroll
    for (int hf = 0; hf < 2; hf++) {
      int row40 = (wv * 32 + hf * 16 + l16) * 40;
#pragma unroll
      for (int nt = 0; nt < 2; nt++) {
        float p0 = exp2f(s[hf][nt][0]);
        float p1 = exp2f(s[hf][nt][1]);
        float p2 = exp2f(s[hf][nt][2]);
        float p3 = exp2f(s[hf][nt][3]);
        lsum[hf] += (p0 + p1) + (p2 + p3);
        u64 pk = (u64)f2bf(p0) | ((u64)f2bf(p1) << 16)
               | ((u64)f2bf(p2) << 32) | ((u64)f2bf(p3) << 48);
        *(u64*)&Pb[row40 + nt * 16 + quad * 4] = pk;
      }
    }
    // cross-quad P round-trip: force all P ds_writes to retire before pf ds_reads
    FENCE_LDS();
    // O += P V  (Vc holds V^T: rows = d, cols = 32 keys; K=32 -> one MFMA per tile).
    // pf reads identical to R9 (verified): lane=query l16 reads keys quad*8..+7.
    {
      bf16x8 pf0 = *(const bf16x8*)&Pb[(wv * 32 + l16) * 40 + quad * 8];
      bf16x8 pf1 = *(const bf16x8*)&Pb[(wv * 32 + 16 + l16) * 40 + quad * 8];
#pragma unroll
      for (int nt = 0; nt < 8; nt++) {
        bf16x8 vf = *(const bf16x8*)&Vc[swz32(nt * 16 + l16, quad)];
        o[0][nt] = __builtin_amdgcn_mfma_f32_16x16x32_bf16(pf0, vf, o[0][nt], 0, 0, 0);
        o[1][nt] = __builtin_amdgcn_mfma_f32_16x16x32_bf16(pf1, vf, o[1][nt], 0, 0, 0);
      }
    }
  }
  // epilogue: lsum lives at lane (l16=query) x 4 quads -> reduce across quads, then
  // each output row (query = quad*4+r) pulls its sum via in-group shfl.
#pragma unroll
  for (int hf = 0; hf < 2; hf++) {
    lsum[hf] += __shfl_xor(lsum[hf], 16);
    lsum[hf] += __shfl_xor(lsum[hf], 32);
  }
  u16* obase = out + ((size_t)b * 2048 + q0) * 2048 + hh * 128;
#pragma unroll
  for (int hf = 0; hf < 2; hf++)
#pragma unroll
    for (int r = 0; r < 4; r++) {
      float lv = __shfl(lsum[hf], quad * 4 + r, 16);
      float inv = 1.0f / lv;
      int row = wv * 32 + hf * 16 + quad * 4 + r;
#pragma unroll
      for (int nt = 0; nt < 8; nt++)
        obase[(size_t)row * 2048 + nt * 16 + l16] = f2bf(o[hf][nt][r] * inv);
    }
}

// ---------------- launch ----------------
extern "C" void kernel_launch(void* const* d_in, const int* in_sizes, int n_in,
                              void* d_out, int out_size, void* d_ws, size_t ws_size,
                              hipStream_t stream) {
  const float* x    = (const float*)d_in[0];   // [4,2048,2048]
  const float* cosp = (const float*)d_in[1];   // [2048,128]
  const float* sinp = (const float*)d_in[2];   // [2048,128]
  const float* wqkv = (const float*)d_in[3];   // [6144,2048]
  const float* wout = (const float*)d_in[4];   // [2048,2048]
  float* outp = (float*)d_out;                 // [4,2048,2048] fp32

  u16* ws    = (u16*)d_ws;
  u16* xb    = ws;                     // 16,777,216 elems (dead after gemm_qkv; reused)
  u16* wqkvb = xb + 16777216;          // 12,582,912 (row-permuted q/k)
  u16* woutb = wqkvb + 12582912;       //  4,194,304
  u16* qkv   = woutb + 4194304;        // 33,554,432 (q,k only; row stride 4096)
  u16* vt    = qkv + 33554432;         // 16,777,216
  float2* cs = (float2*)(vt + 16777216); // 131,072 float2 = 1 MB
  u16* attn  = xb;                     // alias: xb dead after gemm_qkv

  prep<<<32896, 256, 0, stream>>>(x, wqkv, wout, cosp, sinp, xb, wqkvb, woutb, cs);
  gemm_qkv<<<768, 512, 0, stream>>>(xb, wqkvb, qkv, vt, cs);
  attn_fused<<<1024, 256, 0, stream>>>(qkv, vt, attn);
  gemm_out_k<<<256, 512, 0, stream>>>(attn, woutb, outp);
}